// Round 6
// baseline (427.796 us; speedup 1.0000x reference)
//
#include <hip/hip_runtime.h>
#include <math.h>

#define HID 1024
#define NROWS 2048

typedef __attribute__((ext_vector_type(8))) short short8;
typedef __attribute__((ext_vector_type(4))) short short4_t;
typedef __attribute__((ext_vector_type(4))) float f32x4;

__device__ __forceinline__ short f2bf(float f) {
  union { float f; unsigned u; } v; v.f = f;
  unsigned r = v.u + 0x7fffu + ((v.u >> 16) & 1u);
  return (short)(r >> 16);
}
__device__ __forceinline__ float bf2f(short s) {
  union { unsigned u; float f; } v; v.u = ((unsigned)(unsigned short)s) << 16;
  return v.f;
}
__device__ __forceinline__ float wave_sum(float a) {
#pragma unroll
  for (int off = 32; off; off >>= 1) a += __shfl_xor(a, off, 64);
  return a;
}

// ---------------------------------------------------------------------------
// Shared 32x32 transpose-convert tile: W fp32 [K,N] -> BT bf16 [Npad,K].
// ---------------------------------------------------------------------------
__device__ __forceinline__ void transpose_tile(const float* __restrict__ W,
                                               short* __restrict__ BT,
                                               int K, int N, int Npad, int tn,
                                               int b, int tid) {
  __shared__ float T[32][33];
  const int n0 = (b % tn) * 32, k0 = (b / tn) * 32;
  const int r = tid >> 3, c = (tid & 7) * 4;
  float v0 = 0.f, v1 = 0.f, v2 = 0.f, v3 = 0.f;
  const float* p = &W[(size_t)(k0 + r) * N];
  if (n0 + c + 3 < N) {
    v0 = p[n0 + c]; v1 = p[n0 + c + 1]; v2 = p[n0 + c + 2]; v3 = p[n0 + c + 3];
  } else {
    if (n0 + c + 0 < N) v0 = p[n0 + c + 0];
    if (n0 + c + 1 < N) v1 = p[n0 + c + 1];
    if (n0 + c + 2 < N) v2 = p[n0 + c + 2];
  }
  T[r][c] = v0; T[r][c + 1] = v1; T[r][c + 2] = v2; T[r][c + 3] = v3;
  __syncthreads();
  const int nl = tid >> 3, kl = (tid & 7) * 4;
  const int n = n0 + nl;
  if (n < Npad) {
    short4_t o;
    o.x = (n < N) ? f2bf(T[kl + 0][nl]) : (short)0;
    o.y = (n < N) ? f2bf(T[kl + 1][nl]) : (short)0;
    o.z = (n < N) ? f2bf(T[kl + 2][nl]) : (short)0;
    o.w = (n < N) ? f2bf(T[kl + 3][nl]) : (short)0;
    *(short4_t*)&BT[(size_t)n * K + k0 + kl] = o;
  }
}

// ---------------------------------------------------------------------------
// PREP1: block 0 = classify; 1..2048 = x cvt; 2049..3456 = Wp transposes.
// ---------------------------------------------------------------------------
__global__ __launch_bounds__(256) void prep1(
    const float* __restrict__ x, const int* __restrict__ y,
    const float* __restrict__ Wp0, const float* __restrict__ Wp1,
    const float* __restrict__ Wp2,
    short* __restrict__ xb,
    int* __restrict__ counts, int* __restrict__ slot_of_row,
    int* __restrict__ rows1, int* __restrict__ rows2,
    short* __restrict__ T0, short* __restrict__ T1, short* __restrict__ T2) {
  const int tid = threadIdx.x;
  int b = blockIdx.x;
  if (b == 0) {
    __shared__ int c1s, c2s;
    if (tid == 0) { c1s = 0; c2s = 0; }
    __syncthreads();
    for (int r = tid; r < NROWS; r += 256) {
      const int yy = y[r];
      if (yy >= 20000) {
        const int s = atomicAdd(&c2s, 1);
        slot_of_row[r] = s; rows2[s] = r;
      } else if (yy >= 10000) {
        const int s = atomicAdd(&c1s, 1);
        slot_of_row[r] = s; rows1[s] = r;
      } else {
        slot_of_row[r] = -1;
      }
    }
    __syncthreads();
    if (tid == 0) { counts[0] = NROWS; counts[1] = c1s; counts[2] = c2s; }
    return;
  }
  if (b <= 2048) {
    const int i = ((b - 1) * 256 + tid) * 4;
    short4_t o;
    o.x = f2bf(x[i + 0]); o.y = f2bf(x[i + 1]);
    o.z = f2bf(x[i + 2]); o.w = f2bf(x[i + 3]);
    *(short4_t*)&xb[i] = o;
    return;
  }
  b -= 2049;
  if (b < 1024)               transpose_tile(Wp0, T0, 1024, 1024, 1024, 32, b, tid);
  else if ((b -= 1024) < 256) transpose_tile(Wp1, T1, 1024, 256, 256, 8, b, tid);
  else { b -= 256;            transpose_tile(Wp2, T2, 1024, 64, 128, 4, b, tid); }
}

// ---------------------------------------------------------------------------
// MFMA main loop: 128x128 tile, BK=64, XOR-swizzled LDS (verified 0 conflicts).
// ---------------------------------------------------------------------------
__device__ __forceinline__ void mfma_mainloop(const short* aB[4], const short* bB[4],
                                              short* As, short* Bs,
                                              f32x4 acc[4][4],
                                              int K, int w, int lane) {
  const int quad = lane >> 4, ln = lane & 15;
  const int wm = w >> 1, wn = w & 1;
  const int l7 = ln & 7;
  for (int kt = 0; kt < K; kt += 64) {
#pragma unroll
    for (int i = 0; i < 4; ++i) {
      const int row = w * 32 + i * 8;
      __builtin_amdgcn_global_load_lds(
          (const __attribute__((address_space(1))) void*)(aB[i] + kt),
          (__attribute__((address_space(3))) void*)(As + row * 64), 16, 0, 0);
      __builtin_amdgcn_global_load_lds(
          (const __attribute__((address_space(1))) void*)(bB[i] + kt),
          (__attribute__((address_space(3))) void*)(Bs + row * 64), 16, 0, 0);
    }
    __syncthreads();
#pragma unroll
    for (int ks = 0; ks < 2; ++ks) {
      const int kcs = ks * 4 + quad;
      short8 af[4], bfr[4];
#pragma unroll
      for (int mt = 0; mt < 4; ++mt) {
        const int row = wm * 64 + mt * 16 + ln;
        af[mt] = *(const short8*)(As + ((row * 8 + (kcs ^ l7)) << 3));
      }
#pragma unroll
      for (int nt = 0; nt < 4; ++nt) {
        const int rowb = wn * 64 + nt * 16 + ln;
        bfr[nt] = *(const short8*)(Bs + ((rowb * 8 + (kcs ^ l7)) << 3));
      }
#pragma unroll
      for (int mt = 0; mt < 4; ++mt)
#pragma unroll
        for (int nt = 0; nt < 4; ++nt)
          acc[mt][nt] = __builtin_amdgcn_mfma_f32_16x16x32_bf16(
              af[mt], bfr[nt], acc[mt][nt], 0, 0, 0);
    }
    __syncthreads();
  }
}

// C/D layout: col = lane&15, row = (lane>>4)*4 + reg   [verified m89/m91]

// ---------------------------------------------------------------------------
// LAUNCH2: blocks 0..175 = proj tiles (head 128, tail1 32, tail2 16, inline
// row-gather for tails); blocks 176.. = Wl transposes (10112+7520+3256).
// Proj tiles dispatch first and co-run with the BW-bound transpose blocks.
// Grid = 176 + 20888 = 21064.
// ---------------------------------------------------------------------------
__global__ __launch_bounds__(256) void launch2(
    const short* __restrict__ xb,
    const short* __restrict__ WpT0, const short* __restrict__ WpT1,
    const short* __restrict__ WpT2,
    short* __restrict__ P0b, short* __restrict__ P1c, short* __restrict__ P2c,
    const int* __restrict__ rows1, const int* __restrict__ rows2,
    const int* __restrict__ counts,
    const float* __restrict__ Wl0, const float* __restrict__ Wl1,
    const float* __restrict__ Wl2,
    short* __restrict__ WlT0, short* __restrict__ WlT1,
    short* __restrict__ WlT2) {
  int b = blockIdx.x;
  const int tid = threadIdx.x;
  if (b >= 176) {                       // ---- Wl transposes ----
    b -= 176;
    if (b < 10112)               transpose_tile(Wl0, WlT0, 1024, 10000, 10112, 316, b, tid);
    else if ((b -= 10112) < 7520) transpose_tile(Wl1, WlT1, 256, 30000, 30080, 940, b, tid);
    else { b -= 7520;             transpose_tile(Wl2, WlT2, 64, 52000, 52096, 1628, b, tid); }
    return;
  }
  // ---- proj tiles ----
  const short* BT; short* C; int N, r0, c0, cnt;
  const int* rowlist = nullptr;
  if (b < 128) {
    BT = WpT0; C = P0b; N = 1024;
    c0 = (b & 7) * 128; r0 = (b >> 3) * 128; cnt = NROWS;
  } else if (b < 160) {
    b -= 128; BT = WpT1; C = P1c; N = 256;
    c0 = (b & 1) * 128; r0 = (b >> 1) * 128; rowlist = rows1; cnt = counts[1];
  } else {
    b -= 160; BT = WpT2; C = P2c; N = 64;
    c0 = 0; r0 = b * 128; rowlist = rows2; cnt = counts[2];
  }
  if (r0 >= cnt) return;

  __shared__ short As[128 * 64];
  __shared__ short Bs[128 * 64];
  const int w = tid >> 6, lane = tid & 63;
  const int quad = lane >> 4, ln = lane & 15;
  const int wm = w >> 1, wn = w & 1;
  const int rsub = lane >> 3;
  const int kc = (lane & 7) ^ rsub;
  const int K = 1024;

  const short* aB[4]; const short* bB[4];
#pragma unroll
  for (int i = 0; i < 4; ++i) {
    const int sl = r0 + w * 32 + i * 8 + rsub;
    const int ar = rowlist ? rowlist[sl < cnt ? sl : cnt - 1] : sl;
    aB[i] = xb + (size_t)ar * K + kc * 8;
    bB[i] = BT + (size_t)(c0 + w * 32 + i * 8 + rsub) * K + kc * 8;
  }

  f32x4 acc[4][4];
  const f32x4 zero = {0.f, 0.f, 0.f, 0.f};
#pragma unroll
  for (int i = 0; i < 4; ++i)
#pragma unroll
    for (int j = 0; j < 4; ++j) acc[i][j] = zero;
  mfma_mainloop(aB, bB, As, Bs, acc, K, w, lane);
#pragma unroll
  for (int mt = 0; mt < 4; ++mt)
#pragma unroll
    for (int r = 0; r < 4; ++r) {
      const int grow = r0 + wm * 64 + mt * 16 + quad * 4 + r;
#pragma unroll
      for (int nt = 0; nt < 4; ++nt) {
        const int cg = c0 + wn * 64 + nt * 16 + ln;
        if (cg < N) C[(size_t)grow * N + cg] = f2bf(acc[mt][nt][r]);
      }
    }
}

// ---------------------------------------------------------------------------
// LOGIT_PERSIST: 1280 persistent blocks (5/CU; LDS exactly 32 KiB via psL
// aliased into As). xcd = blockIdx&7 owns exclusive cs-slices (L2-resident
// B). Each block strides over its XCD's real tile list (no dead blocks).
// Emits per-(row, 128-col-split) sum-of-exp partials.
// ---------------------------------------------------------------------------
__global__ __launch_bounds__(256, 5) void logit_persist(
    const short* __restrict__ P0b, const short* __restrict__ WlT0,
    const float* __restrict__ bl0, float* __restrict__ psh,
    const short* __restrict__ P1c, const short* __restrict__ WlT1,
    const float* __restrict__ bl1, float* __restrict__ ps1,
    const short* __restrict__ P2c, const short* __restrict__ WlT2,
    const float* __restrict__ bl2, float* __restrict__ ps2,
    const int* __restrict__ counts) {
  __shared__ short As[128 * 64];
  __shared__ short Bs[128 * 64];
  float* psL = (float*)As;              // aliased: used only after mainloop
  const int tid = threadIdx.x;
  const int w = tid >> 6, lane = tid & 63;
  const int quad = lane >> 4, ln = lane & 15;
  const int wm = w >> 1, wn = w & 1;
  const int rsub = lane >> 3;
  const int kc = (lane & 7) ^ rsub;

  const int xcd = blockIdx.x & 7;
  const int lid = blockIdx.x >> 3;      // 0..159 within this xcd
  const int nrb1 = (counts[1] + 127) >> 7;
  const int nrb2 = (counts[2] + 127) >> 7;
  const int nch = (xcd < 7) ? 10 : 9;   // 79 head col-splits
  const int nc1 = (xcd < 7) ? 30 : 25;  // 235 tail1
  const int nc2 = (xcd < 7) ? 51 : 50;  // 407 tail2
  const int nh = nch * 16, n1 = nc1 * nrb1, n2 = nc2 * nrb2;
  const int T = nh + n1 + n2;

  for (int t = lid; t < T; t += 160) {
    const short* A; const short* BT; const float* bias; float* ps;
    int K, Ncols, nsplit, rb, cs;
    int tt = t;
    if (tt < nh) {                      // head: rb-slow, cs-fast (A reuse)
      rb = tt / nch; cs = xcd * 10 + tt % nch;
      A = P0b; BT = WlT0; bias = bl0; ps = psh;
      K = 1024; Ncols = 10000; nsplit = 79;
    } else if ((tt -= nh) < n1) {       // tail1: cs-slow, rb-fast (B reuse)
      cs = xcd * 30 + tt / nrb1; rb = tt % nrb1;
      A = P1c; BT = WlT1; bias = bl1; ps = ps1;
      K = 256; Ncols = 30000; nsplit = 235;
    } else {
      tt -= n1;
      cs = xcd * 51 + tt / nrb2; rb = tt % nrb2;
      A = P2c; BT = WlT2; bias = bl2; ps = ps2;
      K = 64; Ncols = 52000; nsplit = 407;
    }
    const int r0 = rb * 128, c0 = cs * 128;

    const short* aB[4]; const short* bB[4];
#pragma unroll
    for (int i = 0; i < 4; ++i) {
      aB[i] = A + (size_t)(r0 + w * 32 + i * 8 + rsub) * K + kc * 8;
      bB[i] = BT + (size_t)(c0 + w * 32 + i * 8 + rsub) * K + kc * 8;
    }

    f32x4 acc[4][4];
    const f32x4 zero = {0.f, 0.f, 0.f, 0.f};
#pragma unroll
    for (int i = 0; i < 4; ++i)
#pragma unroll
      for (int j = 0; j < 4; ++j) acc[i][j] = zero;
    __syncthreads();                    // psL (As) free before restage
    mfma_mainloop(aB, bB, As, Bs, acc, K, w, lane);

    float bv[4];
#pragma unroll
    for (int nt = 0; nt < 4; ++nt) {
      const int cg = c0 + wn * 64 + nt * 16 + ln;
      bv[nt] = (cg < Ncols) ? bias[cg] : -1.0e30f;  // pad cols -> exp()=0
    }
#pragma unroll
    for (int mt = 0; mt < 4; ++mt)
#pragma unroll
      for (int r = 0; r < 4; ++r) {
        float s = 0.f;
#pragma unroll
        for (int nt = 0; nt < 4; ++nt)
          s += __expf(acc[mt][nt][r] + bv[nt]);
#pragma unroll
        for (int off = 1; off < 16; off <<= 1) s += __shfl_xor(s, off, 64);
        if (ln == 0) psL[wn * 128 + wm * 64 + mt * 16 + quad * 4 + r] = s;
      }
    __syncthreads();
    if (tid < 128)
      ps[(size_t)(r0 + tid) * nsplit + cs] = psL[tid] + psL[128 + tid];
  }
}

// ---------------------------------------------------------------------------
// FINALIZE: one wave per row (bf16 transposed weights for target dots).
// ---------------------------------------------------------------------------
__global__ __launch_bounds__(256) void finalize(
    const short* __restrict__ P0b, const short* __restrict__ P1c,
    const short* __restrict__ P2c,
    const short* __restrict__ WlT0, const float* __restrict__ bl0,
    const short* __restrict__ WlT1, const float* __restrict__ bl1,
    const short* __restrict__ WlT2, const float* __restrict__ bl2,
    const float* __restrict__ Wc, const float* __restrict__ bc,
    const int* __restrict__ y, const int* __restrict__ slot_of_row,
    const float* __restrict__ psh, const float* __restrict__ ps1,
    const float* __restrict__ ps2, float* __restrict__ out) {
  const int lane = threadIdx.x & 63;
  const int row = blockIdx.x * 4 + (threadIdx.x >> 6);

  float a0 = 0.f, a1 = 0.f;
  for (int k = lane; k < HID; k += 64) {
    const float p = bf2f(P0b[(size_t)row * HID + k]);
    a0 += p * Wc[2 * k];
    a1 += p * Wc[2 * k + 1];
  }
  a0 = wave_sum(a0);
  a1 = wave_sum(a1);
  const float cl0 = a0 + bc[0], cl1 = a1 + bc[1];

  float S = 0.f;
  for (int i = lane; i < 79; i += 64) S += psh[(size_t)row * 79 + i];
  S = wave_sum(S) + __expf(cl0) + __expf(cl1);
  const float lse = logf(S);

  const int yy = y[row];
  float nll;
  if (yy < 10000) {
    const short* pr = P0b + (size_t)row * 1024;
    const short* wr = WlT0 + (size_t)yy * 1024;
    float a = 0.f;
    for (int kk = lane * 4; kk < 1024; kk += 256) {
      const short4_t p = *(const short4_t*)(pr + kk);
      const short4_t wv = *(const short4_t*)(wr + kk);
      a += bf2f(p.x) * bf2f(wv.x) + bf2f(p.y) * bf2f(wv.y)
         + bf2f(p.z) * bf2f(wv.z) + bf2f(p.w) * bf2f(wv.w);
    }
    a = wave_sum(a);
    nll = -((a + bl0[yy]) - lse);
  } else if (yy < 20000) {
    const int t = yy - 10000;
    const int slot = slot_of_row[row];
    float S1 = 0.f;
    for (int i = lane; i < 235; i += 64) S1 += ps1[(size_t)slot * 235 + i];
    S1 = wave_sum(S1);
    const short* pr = P1c + (size_t)slot * 256;
    const short* wr = WlT1 + (size_t)t * 256;
    const int kk = lane * 4;
    const short4_t p = *(const short4_t*)(pr + kk);
    const short4_t wv = *(const short4_t*)(wr + kk);
    float a = bf2f(p.x) * bf2f(wv.x) + bf2f(p.y) * bf2f(wv.y)
            + bf2f(p.z) * bf2f(wv.z) + bf2f(p.w) * bf2f(wv.w);
    a = wave_sum(a);
    nll = -((cl1 - lse) + ((a + bl1[t]) - logf(S1)));
  } else {
    const int t = yy - 20000;
    const int slot = slot_of_row[row];
    float S2 = 0.f;
    for (int i = lane; i < 407; i += 64) S2 += ps2[(size_t)slot * 407 + i];
    S2 = wave_sum(S2);
    float a = 0.f;
    if (lane < 16) {
      const short* pr = P2c + (size_t)slot * 64;
      const short* wr = WlT2 + (size_t)t * 64;
      const int kk = lane * 4;
      const short4_t p = *(const short4_t*)(pr + kk);
      const short4_t wv = *(const short4_t*)(wr + kk);
      a = bf2f(p.x) * bf2f(wv.x) + bf2f(p.y) * bf2f(wv.y)
        + bf2f(p.z) * bf2f(wv.z) + bf2f(p.w) * bf2f(wv.w);
    }
    a = wave_sum(a);
    nll = -((cl0 - lse) + ((a + bl2[t]) - logf(S2)));
  }
  if (lane == 0) out[row] = nll;
}

// ---------------------------------------------------------------------------
extern "C" void kernel_launch(void* const* d_in, const int* in_sizes, int n_in,
                              void* d_out, int out_size, void* d_ws, size_t ws_size,
                              hipStream_t stream) {
  const float* x   = (const float*)d_in[0];
  const int*   y   = (const int*)d_in[1];
  const float* Wp0 = (const float*)d_in[2];
  const float* Wp1 = (const float*)d_in[3];
  const float* Wp2 = (const float*)d_in[4];
  const float* Wl0 = (const float*)d_in[5];
  const float* bl0 = (const float*)d_in[6];
  const float* Wl1 = (const float*)d_in[7];
  const float* bl1 = (const float*)d_in[8];
  const float* Wl2 = (const float*)d_in[9];
  const float* bl2 = (const float*)d_in[10];
  const float* Wc  = (const float*)d_in[11];
  const float* bc  = (const float*)d_in[12];
  float* out = (float*)d_out;

  float* fws = (float*)d_ws;
  float* psh = fws; fws += (size_t)NROWS * 79;
  float* ps1 = fws; fws += (size_t)NROWS * 235;
  float* ps2 = fws; fws += (size_t)NROWS * 407;
  int* iws = (int*)fws;
  int* counts      = iws; iws += 4;
  int* slot_of_row = iws; iws += NROWS;
  int* rows1       = iws; iws += NROWS;
  int* rows2       = iws; iws += NROWS;
  short* sp = (short*)iws;
  short* xb   = sp; sp += (size_t)NROWS * 1024;
  short* P0b  = sp; sp += (size_t)NROWS * 1024;
  short* P1c  = sp; sp += (size_t)NROWS * 256;
  short* P2c  = sp; sp += (size_t)NROWS * 64;
  short* WpT0 = sp; sp += (size_t)1024 * 1024;
  short* WpT1 = sp; sp += (size_t)256 * 1024;
  short* WpT2 = sp; sp += (size_t)128 * 1024;
  short* WlT0 = sp; sp += (size_t)10112 * 1024;
  short* WlT1 = sp; sp += (size_t)30080 * 256;
  short* WlT2 = sp; sp += (size_t)52096 * 64;

  dim3 blk(256);
  prep1<<<dim3(3457), blk, 0, stream>>>(x, y, Wp0, Wp1, Wp2, xb,
                                        counts, slot_of_row, rows1, rows2,
                                        WpT0, WpT1, WpT2);
  launch2<<<dim3(21064), blk, 0, stream>>>(xb, WpT0, WpT1, WpT2,
                                           P0b, P1c, P2c, rows1, rows2, counts,
                                           Wl0, Wl1, Wl2, WlT0, WlT1, WlT2);
  logit_persist<<<dim3(1280), blk, 0, stream>>>(
      P0b, WlT0, bl0, psh, P1c, WlT1, bl1, ps1, P2c, WlT2, bl2, ps2, counts);
  finalize<<<dim3(NROWS / 4), blk, 0, stream>>>(
      P0b, P1c, P2c, WlT0, bl0, WlT1, bl1, WlT2, bl2, Wc, bc, y, slot_of_row,
      psh, ps1, ps2, out);
}

// Round 7
// 320.126 us; speedup vs baseline: 1.3363x; 1.3363x over previous
//
#include <hip/hip_runtime.h>
#include <math.h>

#define HID 1024
#define NROWS 2048

typedef __attribute__((ext_vector_type(8))) short short8;
typedef __attribute__((ext_vector_type(4))) short short4_t;
typedef __attribute__((ext_vector_type(4))) float f32x4;

__device__ __forceinline__ short f2bf(float f) {
  union { float f; unsigned u; } v; v.f = f;
  unsigned r = v.u + 0x7fffu + ((v.u >> 16) & 1u);
  return (short)(r >> 16);
}
__device__ __forceinline__ float bf2f(short s) {
  union { unsigned u; float f; } v; v.u = ((unsigned)(unsigned short)s) << 16;
  return v.f;
}
__device__ __forceinline__ float wave_sum(float a) {
#pragma unroll
  for (int off = 32; off; off >>= 1) a += __shfl_xor(a, off, 64);
  return a;
}

// ---------------------------------------------------------------------------
// Shared 32x32 transpose-convert tile: W fp32 [K,N] -> BT bf16 [Npad,K].
// ---------------------------------------------------------------------------
__device__ __forceinline__ void transpose_tile(const float* __restrict__ W,
                                               short* __restrict__ BT,
                                               int K, int N, int Npad, int tn,
                                               int b, int tid) {
  __shared__ float T[32][33];
  const int n0 = (b % tn) * 32, k0 = (b / tn) * 32;
  const int r = tid >> 3, c = (tid & 7) * 4;
  float v0 = 0.f, v1 = 0.f, v2 = 0.f, v3 = 0.f;
  const float* p = &W[(size_t)(k0 + r) * N];
  if (n0 + c + 3 < N) {
    v0 = p[n0 + c]; v1 = p[n0 + c + 1]; v2 = p[n0 + c + 2]; v3 = p[n0 + c + 3];
  } else {
    if (n0 + c + 0 < N) v0 = p[n0 + c + 0];
    if (n0 + c + 1 < N) v1 = p[n0 + c + 1];
    if (n0 + c + 2 < N) v2 = p[n0 + c + 2];
  }
  T[r][c] = v0; T[r][c + 1] = v1; T[r][c + 2] = v2; T[r][c + 3] = v3;
  __syncthreads();
  const int nl = tid >> 3, kl = (tid & 7) * 4;
  const int n = n0 + nl;
  if (n < Npad) {
    short4_t o;
    o.x = (n < N) ? f2bf(T[kl + 0][nl]) : (short)0;
    o.y = (n < N) ? f2bf(T[kl + 1][nl]) : (short)0;
    o.z = (n < N) ? f2bf(T[kl + 2][nl]) : (short)0;
    o.w = (n < N) ? f2bf(T[kl + 3][nl]) : (short)0;
    *(short4_t*)&BT[(size_t)n * K + k0 + kl] = o;
  }
}

// ---------------------------------------------------------------------------
// PREP1: block 0 = classify; 1..2048 = x cvt; 2049..3456 = Wp transposes.
// ---------------------------------------------------------------------------
__global__ __launch_bounds__(256) void prep1(
    const float* __restrict__ x, const int* __restrict__ y,
    const float* __restrict__ Wp0, const float* __restrict__ Wp1,
    const float* __restrict__ Wp2,
    short* __restrict__ xb,
    int* __restrict__ counts, int* __restrict__ slot_of_row,
    int* __restrict__ rows1, int* __restrict__ rows2,
    short* __restrict__ T0, short* __restrict__ T1, short* __restrict__ T2) {
  const int tid = threadIdx.x;
  int b = blockIdx.x;
  if (b == 0) {
    __shared__ int c1s, c2s;
    if (tid == 0) { c1s = 0; c2s = 0; }
    __syncthreads();
    for (int r = tid; r < NROWS; r += 256) {
      const int yy = y[r];
      if (yy >= 20000) {
        const int s = atomicAdd(&c2s, 1);
        slot_of_row[r] = s; rows2[s] = r;
      } else if (yy >= 10000) {
        const int s = atomicAdd(&c1s, 1);
        slot_of_row[r] = s; rows1[s] = r;
      } else {
        slot_of_row[r] = -1;
      }
    }
    __syncthreads();
    if (tid == 0) { counts[0] = NROWS; counts[1] = c1s; counts[2] = c2s; }
    return;
  }
  if (b <= 2048) {
    const int i = ((b - 1) * 256 + tid) * 4;
    short4_t o;
    o.x = f2bf(x[i + 0]); o.y = f2bf(x[i + 1]);
    o.z = f2bf(x[i + 2]); o.w = f2bf(x[i + 3]);
    *(short4_t*)&xb[i] = o;
    return;
  }
  b -= 2049;
  if (b < 1024)               transpose_tile(Wp0, T0, 1024, 1024, 1024, 32, b, tid);
  else if ((b -= 1024) < 256) transpose_tile(Wp1, T1, 1024, 256, 256, 8, b, tid);
  else { b -= 256;            transpose_tile(Wp2, T2, 1024, 64, 128, 4, b, tid); }
}

// ---------------------------------------------------------------------------
// MFMA main loop (runtime-K variant for proj): 128x128 tile, BK=64,
// XOR-swizzled LDS (verified 0 conflicts).
// ---------------------------------------------------------------------------
__device__ __forceinline__ void mfma_mainloop(const short* aB[4], const short* bB[4],
                                              short* As, short* Bs,
                                              f32x4 acc[4][4],
                                              int K, int w, int lane) {
  const int quad = lane >> 4, ln = lane & 15;
  const int wm = w >> 1, wn = w & 1;
  const int l7 = ln & 7;
  for (int kt = 0; kt < K; kt += 64) {
#pragma unroll
    for (int i = 0; i < 4; ++i) {
      const int row = w * 32 + i * 8;
      __builtin_amdgcn_global_load_lds(
          (const __attribute__((address_space(1))) void*)(aB[i] + kt),
          (__attribute__((address_space(3))) void*)(As + row * 64), 16, 0, 0);
      __builtin_amdgcn_global_load_lds(
          (const __attribute__((address_space(1))) void*)(bB[i] + kt),
          (__attribute__((address_space(3))) void*)(Bs + row * 64), 16, 0, 0);
    }
    __syncthreads();
#pragma unroll
    for (int ks = 0; ks < 2; ++ks) {
      const int kcs = ks * 4 + quad;
      short8 af[4], bfr[4];
#pragma unroll
      for (int mt = 0; mt < 4; ++mt) {
        const int row = wm * 64 + mt * 16 + ln;
        af[mt] = *(const short8*)(As + ((row * 8 + (kcs ^ l7)) << 3));
      }
#pragma unroll
      for (int nt = 0; nt < 4; ++nt) {
        const int rowb = wn * 64 + nt * 16 + ln;
        bfr[nt] = *(const short8*)(Bs + ((rowb * 8 + (kcs ^ l7)) << 3));
      }
#pragma unroll
      for (int mt = 0; mt < 4; ++mt)
#pragma unroll
        for (int nt = 0; nt < 4; ++nt)
          acc[mt][nt] = __builtin_amdgcn_mfma_f32_16x16x32_bf16(
              af[mt], bfr[nt], acc[mt][nt], 0, 0, 0);
    }
    __syncthreads();
  }
}

// C/D layout: col = lane&15, row = (lane>>4)*4 + reg   [verified m89/m91]

// ---------------------------------------------------------------------------
// LAUNCH2: blocks 0..175 = proj tiles (head 128, tail1 32, tail2 16, inline
// row-gather for tails); blocks 176.. = Wl transposes (10112+7520+3256).
// Grid = 176 + 20888 = 21064.
// ---------------------------------------------------------------------------
__global__ __launch_bounds__(256) void launch2(
    const short* __restrict__ xb,
    const short* __restrict__ WpT0, const short* __restrict__ WpT1,
    const short* __restrict__ WpT2,
    short* __restrict__ P0b, short* __restrict__ P1c, short* __restrict__ P2c,
    const int* __restrict__ rows1, const int* __restrict__ rows2,
    const int* __restrict__ counts,
    const float* __restrict__ Wl0, const float* __restrict__ Wl1,
    const float* __restrict__ Wl2,
    short* __restrict__ WlT0, short* __restrict__ WlT1,
    short* __restrict__ WlT2) {
  int b = blockIdx.x;
  const int tid = threadIdx.x;
  if (b >= 176) {                       // ---- Wl transposes ----
    b -= 176;
    if (b < 10112)               transpose_tile(Wl0, WlT0, 1024, 10000, 10112, 316, b, tid);
    else if ((b -= 10112) < 7520) transpose_tile(Wl1, WlT1, 256, 30000, 30080, 940, b, tid);
    else { b -= 7520;             transpose_tile(Wl2, WlT2, 64, 52000, 52096, 1628, b, tid); }
    return;
  }
  // ---- proj tiles ----
  const short* BT; short* C; int N, r0, c0, cnt;
  const int* rowlist = nullptr;
  if (b < 128) {
    BT = WpT0; C = P0b; N = 1024;
    c0 = (b & 7) * 128; r0 = (b >> 3) * 128; cnt = NROWS;
  } else if (b < 160) {
    b -= 128; BT = WpT1; C = P1c; N = 256;
    c0 = (b & 1) * 128; r0 = (b >> 1) * 128; rowlist = rows1; cnt = counts[1];
  } else {
    b -= 160; BT = WpT2; C = P2c; N = 64;
    c0 = 0; r0 = b * 128; rowlist = rows2; cnt = counts[2];
  }
  if (r0 >= cnt) return;

  __shared__ short As[128 * 64];
  __shared__ short Bs[128 * 64];
  const int w = tid >> 6, lane = tid & 63;
  const int quad = lane >> 4, ln = lane & 15;
  const int wm = w >> 1, wn = w & 1;
  const int rsub = lane >> 3;
  const int kc = (lane & 7) ^ rsub;
  const int K = 1024;

  const short* aB[4]; const short* bB[4];
#pragma unroll
  for (int i = 0; i < 4; ++i) {
    const int sl = r0 + w * 32 + i * 8 + rsub;
    const int ar = rowlist ? rowlist[sl < cnt ? sl : cnt - 1] : sl;
    aB[i] = xb + (size_t)ar * K + kc * 8;
    bB[i] = BT + (size_t)(c0 + w * 32 + i * 8 + rsub) * K + kc * 8;
  }

  f32x4 acc[4][4];
  const f32x4 zero = {0.f, 0.f, 0.f, 0.f};
#pragma unroll
  for (int i = 0; i < 4; ++i)
#pragma unroll
    for (int j = 0; j < 4; ++j) acc[i][j] = zero;
  mfma_mainloop(aB, bB, As, Bs, acc, K, w, lane);
#pragma unroll
  for (int mt = 0; mt < 4; ++mt)
#pragma unroll
    for (int r = 0; r < 4; ++r) {
      const int grow = r0 + wm * 64 + mt * 16 + quad * 4 + r;
#pragma unroll
      for (int nt = 0; nt < 4; ++nt) {
        const int cg = c0 + wn * 64 + nt * 16 + ln;
        if (cg < N) C[(size_t)grow * N + cg] = f2bf(acc[mt][nt][r]);
      }
    }
}

// ---------------------------------------------------------------------------
// Templated logit phase: compile-time K/NCOLS/NSPLIT (full unroll for small
// K, scoped registers per phase). Persistent blocks stride their XCD's tile
// list; psL aliased into As (LDS total 32 KiB).
// ---------------------------------------------------------------------------
template <int K, int NCOLS, int NSPLIT, bool CS_SLOW>
__device__ __forceinline__ void logit_phase(
    const short* __restrict__ A, const short* __restrict__ BT,
    const float* __restrict__ bias, float* __restrict__ ps,
    short* As, short* Bs,
    int nrb, int csbase, int ncs, int lid, int tid) {
  float* psL = (float*)As;              // alias: only touched after mainloop
  const int w = tid >> 6, lane = tid & 63;
  const int quad = lane >> 4, ln = lane & 15;
  const int wm = w >> 1, wn = w & 1;
  const int rsub = lane >> 3;
  const int kc = (lane & 7) ^ rsub;
  const int l7 = ln & 15 & 7;
  const int T = nrb * ncs;
  for (int t = lid; t < T; t += 128) {
    const int rb = CS_SLOW ? (t % nrb) : (t / ncs);
    const int cs = csbase + (CS_SLOW ? (t / nrb) : (t % ncs));
    const int r0 = rb * 128, c0 = cs * 128;

    const short* aB[4]; const short* bB[4];
#pragma unroll
    for (int i = 0; i < 4; ++i) {
      aB[i] = A + (size_t)(r0 + w * 32 + i * 8 + rsub) * K + kc * 8;
      bB[i] = BT + (size_t)(c0 + w * 32 + i * 8 + rsub) * K + kc * 8;
    }
    f32x4 acc[4][4];
    const f32x4 zero = {0.f, 0.f, 0.f, 0.f};
#pragma unroll
    for (int i = 0; i < 4; ++i)
#pragma unroll
      for (int j = 0; j < 4; ++j) acc[i][j] = zero;

    __syncthreads();                    // psL (As) reads done before restage
    for (int kt = 0; kt < K; kt += 64) {
#pragma unroll
      for (int i = 0; i < 4; ++i) {
        const int row = w * 32 + i * 8;
        __builtin_amdgcn_global_load_lds(
            (const __attribute__((address_space(1))) void*)(aB[i] + kt),
            (__attribute__((address_space(3))) void*)(As + row * 64), 16, 0, 0);
        __builtin_amdgcn_global_load_lds(
            (const __attribute__((address_space(1))) void*)(bB[i] + kt),
            (__attribute__((address_space(3))) void*)(Bs + row * 64), 16, 0, 0);
      }
      __syncthreads();
#pragma unroll
      for (int ks = 0; ks < 2; ++ks) {
        const int kcs = ks * 4 + quad;
        short8 af[4], bfr[4];
#pragma unroll
        for (int mt = 0; mt < 4; ++mt) {
          const int row = wm * 64 + mt * 16 + ln;
          af[mt] = *(const short8*)(As + ((row * 8 + (kcs ^ l7)) << 3));
        }
#pragma unroll
        for (int nt = 0; nt < 4; ++nt) {
          const int rowb = wn * 64 + nt * 16 + ln;
          bfr[nt] = *(const short8*)(Bs + ((rowb * 8 + (kcs ^ l7)) << 3));
        }
#pragma unroll
        for (int mt = 0; mt < 4; ++mt)
#pragma unroll
          for (int nt = 0; nt < 4; ++nt)
            acc[mt][nt] = __builtin_amdgcn_mfma_f32_16x16x32_bf16(
                af[mt], bfr[nt], acc[mt][nt], 0, 0, 0);
      }
      __syncthreads();
    }

    float bv[4];
#pragma unroll
    for (int nt = 0; nt < 4; ++nt) {
      const int cg = c0 + wn * 64 + nt * 16 + ln;
      bv[nt] = (cg < NCOLS) ? bias[cg] : -1.0e30f;  // pad cols -> exp()=0
    }
#pragma unroll
    for (int mt = 0; mt < 4; ++mt)
#pragma unroll
      for (int r = 0; r < 4; ++r) {
        float s = 0.f;
#pragma unroll
        for (int nt = 0; nt < 4; ++nt)
          s += __expf(acc[mt][nt][r] + bv[nt]);
#pragma unroll
        for (int off = 1; off < 16; off <<= 1) s += __shfl_xor(s, off, 64);
        if (ln == 0) psL[wn * 128 + wm * 64 + mt * 16 + quad * 4 + r] = s;
      }
    __syncthreads();
    if (tid < 128)
      ps[(size_t)(r0 + tid) * NSPLIT + cs] = psL[tid] + psL[128 + tid];
  }
}

// ---------------------------------------------------------------------------
// LOGIT_PERSIST v2: 1024 persistent blocks (4/CU), plain launch bounds (no
// forced VGPR cap -> no spill), three sequential compile-time phases.
// xcd = blockIdx&7 owns exclusive cs-slices (L2-resident B, r5-verified).
// ---------------------------------------------------------------------------
__global__ __launch_bounds__(256) void logit_persist(
    const short* __restrict__ P0b, const short* __restrict__ WlT0,
    const float* __restrict__ bl0, float* __restrict__ psh,
    const short* __restrict__ P1c, const short* __restrict__ WlT1,
    const float* __restrict__ bl1, float* __restrict__ ps1,
    const short* __restrict__ P2c, const short* __restrict__ WlT2,
    const float* __restrict__ bl2, float* __restrict__ ps2,
    const int* __restrict__ counts) {
  __shared__ short As[128 * 64];
  __shared__ short Bs[128 * 64];
  const int tid = threadIdx.x;
  const int xcd = blockIdx.x & 7;
  const int lid = blockIdx.x >> 3;      // 0..127 within this xcd
  const int nrb1 = (counts[1] + 127) >> 7;
  const int nrb2 = (counts[2] + 127) >> 7;

  // head: 79 cs over 8 xcds (10/10/10/10/10/10/10/9), rb-slow/cs-fast
  logit_phase<1024, 10000, 79, false>(P0b, WlT0, bl0, psh, As, Bs,
                                      16, xcd * 10, (xcd < 7) ? 10 : 9, lid, tid);
  // tail1: 235 cs (30x7 + 25), cs-slow/rb-fast (B reuse)
  logit_phase<256, 30000, 235, true>(P1c, WlT1, bl1, ps1, As, Bs,
                                     nrb1, xcd * 30, (xcd < 7) ? 30 : 25, lid, tid);
  // tail2: 407 cs (51x7 + 50)
  logit_phase<64, 52000, 407, true>(P2c, WlT2, bl2, ps2, As, Bs,
                                    nrb2, xcd * 51, (xcd < 7) ? 51 : 50, lid, tid);
}

// ---------------------------------------------------------------------------
// FINALIZE: one wave per row (bf16 transposed weights for target dots).
// ---------------------------------------------------------------------------
__global__ __launch_bounds__(256) void finalize(
    const short* __restrict__ P0b, const short* __restrict__ P1c,
    const short* __restrict__ P2c,
    const short* __restrict__ WlT0, const float* __restrict__ bl0,
    const short* __restrict__ WlT1, const float* __restrict__ bl1,
    const short* __restrict__ WlT2, const float* __restrict__ bl2,
    const float* __restrict__ Wc, const float* __restrict__ bc,
    const int* __restrict__ y, const int* __restrict__ slot_of_row,
    const float* __restrict__ psh, const float* __restrict__ ps1,
    const float* __restrict__ ps2, float* __restrict__ out) {
  const int lane = threadIdx.x & 63;
  const int row = blockIdx.x * 4 + (threadIdx.x >> 6);

  float a0 = 0.f, a1 = 0.f;
  for (int k = lane; k < HID; k += 64) {
    const float p = bf2f(P0b[(size_t)row * HID + k]);
    a0 += p * Wc[2 * k];
    a1 += p * Wc[2 * k + 1];
  }
  a0 = wave_sum(a0);
  a1 = wave_sum(a1);
  const float cl0 = a0 + bc[0], cl1 = a1 + bc[1];

  float S = 0.f;
  for (int i = lane; i < 79; i += 64) S += psh[(size_t)row * 79 + i];
  S = wave_sum(S) + __expf(cl0) + __expf(cl1);
  const float lse = logf(S);

  const int yy = y[row];
  float nll;
  if (yy < 10000) {
    const short* pr = P0b + (size_t)row * 1024;
    const short* wr = WlT0 + (size_t)yy * 1024;
    float a = 0.f;
    for (int kk = lane * 4; kk < 1024; kk += 256) {
      const short4_t p = *(const short4_t*)(pr + kk);
      const short4_t wv = *(const short4_t*)(wr + kk);
      a += bf2f(p.x) * bf2f(wv.x) + bf2f(p.y) * bf2f(wv.y)
         + bf2f(p.z) * bf2f(wv.z) + bf2f(p.w) * bf2f(wv.w);
    }
    a = wave_sum(a);
    nll = -((a + bl0[yy]) - lse);
  } else if (yy < 20000) {
    const int t = yy - 10000;
    const int slot = slot_of_row[row];
    float S1 = 0.f;
    for (int i = lane; i < 235; i += 64) S1 += ps1[(size_t)slot * 235 + i];
    S1 = wave_sum(S1);
    const short* pr = P1c + (size_t)slot * 256;
    const short* wr = WlT1 + (size_t)t * 256;
    const int kk = lane * 4;
    const short4_t p = *(const short4_t*)(pr + kk);
    const short4_t wv = *(const short4_t*)(wr + kk);
    float a = bf2f(p.x) * bf2f(wv.x) + bf2f(p.y) * bf2f(wv.y)
            + bf2f(p.z) * bf2f(wv.z) + bf2f(p.w) * bf2f(wv.w);
    a = wave_sum(a);
    nll = -((cl1 - lse) + ((a + bl1[t]) - logf(S1)));
  } else {
    const int t = yy - 20000;
    const int slot = slot_of_row[row];
    float S2 = 0.f;
    for (int i = lane; i < 407; i += 64) S2 += ps2[(size_t)slot * 407 + i];
    S2 = wave_sum(S2);
    float a = 0.f;
    if (lane < 16) {
      const short* pr = P2c + (size_t)slot * 64;
      const short* wr = WlT2 + (size_t)t * 64;
      const int kk = lane * 4;
      const short4_t p = *(const short4_t*)(pr + kk);
      const short4_t wv = *(const short4_t*)(wr + kk);
      a = bf2f(p.x) * bf2f(wv.x) + bf2f(p.y) * bf2f(wv.y)
        + bf2f(p.z) * bf2f(wv.z) + bf2f(p.w) * bf2f(wv.w);
    }
    a = wave_sum(a);
    nll = -((cl0 - lse) + ((a + bl2[t]) - logf(S2)));
  }
  if (lane == 0) out[row] = nll;
}

// ---------------------------------------------------------------------------
extern "C" void kernel_launch(void* const* d_in, const int* in_sizes, int n_in,
                              void* d_out, int out_size, void* d_ws, size_t ws_size,
                              hipStream_t stream) {
  const float* x   = (const float*)d_in[0];
  const int*   y   = (const int*)d_in[1];
  const float* Wp0 = (const float*)d_in[2];
  const float* Wp1 = (const float*)d_in[3];
  const float* Wp2 = (const float*)d_in[4];
  const float* Wl0 = (const float*)d_in[5];
  const float* bl0 = (const float*)d_in[6];
  const float* Wl1 = (const float*)d_in[7];
  const float* bl1 = (const float*)d_in[8];
  const float* Wl2 = (const float*)d_in[9];
  const float* bl2 = (const float*)d_in[10];
  const float* Wc  = (const float*)d_in[11];
  const float* bc  = (const float*)d_in[12];
  float* out = (float*)d_out;

  float* fws = (float*)d_ws;
  float* psh = fws; fws += (size_t)NROWS * 79;
  float* ps1 = fws; fws += (size_t)NROWS * 235;
  float* ps2 = fws; fws += (size_t)NROWS * 407;
  int* iws = (int*)fws;
  int* counts      = iws; iws += 4;
  int* slot_of_row = iws; iws += NROWS;
  int* rows1       = iws; iws += NROWS;
  int* rows2       = iws; iws += NROWS;
  short* sp = (short*)iws;
  short* xb   = sp; sp += (size_t)NROWS * 1024;
  short* P0b  = sp; sp += (size_t)NROWS * 1024;
  short* P1c  = sp; sp += (size_t)NROWS * 256;
  short* P2c  = sp; sp += (size_t)NROWS * 64;
  short* WpT0 = sp; sp += (size_t)1024 * 1024;
  short* WpT1 = sp; sp += (size_t)256 * 1024;
  short* WpT2 = sp; sp += (size_t)128 * 1024;
  short* WlT0 = sp; sp += (size_t)10112 * 1024;
  short* WlT1 = sp; sp += (size_t)30080 * 256;
  short* WlT2 = sp; sp += (size_t)52096 * 64;

  dim3 blk(256);
  prep1<<<dim3(3457), blk, 0, stream>>>(x, y, Wp0, Wp1, Wp2, xb,
                                        counts, slot_of_row, rows1, rows2,
                                        WpT0, WpT1, WpT2);
  launch2<<<dim3(21064), blk, 0, stream>>>(xb, WpT0, WpT1, WpT2,
                                           P0b, P1c, P2c, rows1, rows2, counts,
                                           Wl0, Wl1, Wl2, WlT0, WlT1, WlT2);
  logit_persist<<<dim3(1024), blk, 0, stream>>>(
      P0b, WlT0, bl0, psh, P1c, WlT1, bl1, ps1, P2c, WlT2, bl2, ps2, counts);
  finalize<<<dim3(NROWS / 4), blk, 0, stream>>>(
      P0b, P1c, P2c, WlT0, bl0, WlT1, bl1, WlT2, bl2, Wc, bc, y, slot_of_row,
      psh, ps1, ps2, out);
}